// Round 8
// baseline (82.433 us; speedup 1.0000x reference)
//
#include <hip/hip_runtime.h>
#include <hip/hip_bf16.h>
#include <stdint.h>

typedef __attribute__((ext_vector_type(4))) float  f32x4;
typedef __attribute__((ext_vector_type(8))) short  s16x8;
typedef __attribute__((ext_vector_type(4))) int    i32x4;
typedef __attribute__((ext_vector_type(4))) unsigned int u32x4;

#define NN 4096
#define GT_LD 4096
#define NUM_STRIDE (4096 * 512)

__device__ __forceinline__ unsigned short f2bf(float f) {
  uint32_t u = __builtin_bit_cast(uint32_t, f);
  u += 0x7FFF + ((u >> 16) & 1);           // RNE
  return (unsigned short)(u >> 16);
}

__device__ __forceinline__ void gload_lds16(const void* g, void* l) {
  __builtin_amdgcn_global_load_lds(
      (const __attribute__((address_space(1))) unsigned int*)g,
      (__attribute__((address_space(3))) unsigned int*)l, 16, 0, 0);
}

// ---- kernel A: conv_x + conv_wt fused (block ranges) --------------------
__global__ __launch_bounds__(512) void k_small(const float* __restrict__ x,
                                               const float* __restrict__ W,
                                               unsigned short* __restrict__ xb,
                                               unsigned short* __restrict__ wt) {
  int bid = blockIdx.x;
  if (bid < 512) {                          // x f32 -> bf16, 4/thread
    int t = bid * 512 + threadIdx.x;
    f32x4 v = ((const f32x4*)x)[t];
    uint64_t r = (uint64_t)f2bf(v.x) | ((uint64_t)f2bf(v.y) << 16) |
                 ((uint64_t)f2bf(v.z) << 32) | ((uint64_t)f2bf(v.w) << 48);
    ((uint64_t*)xb)[t] = r;
  } else {                                  // W (256x512) -> W^T (512x256) bf16
    int t = (bid - 512) * 512 + threadIdx.x;
    int c = t >> 8, k = t & 255;
    wt[t] = f2bf(W[k * 512 + c]);
  }
}

// ---- kernel B: fat kernel — h_gt blocks [0,256) + adj bit-pack blocks ---
__global__ __launch_bounds__(512) void k_fat(const int* __restrict__ adj,
                                             unsigned int* __restrict__ bits,
                                             const unsigned short* __restrict__ xb,
                                             const unsigned short* __restrict__ wt,
                                             const float* __restrict__ attn,
                                             unsigned short* __restrict__ gt) {
  __shared__ unsigned short lx[16 * 256];   // [16 rows][512B], XOR-swizzled
  __shared__ unsigned short lw[512 * 64];   // [512 cols][128B], XOR-swizzled

  if (blockIdx.x >= 256) {                  // ---- adj row -> 4096 bits ----
    int row = blockIdx.x - 256;             // one row per block
    int w = threadIdx.x >> 6, lane = threadIdx.x & 63;
    const int* ap = adj + row * 4096 + w * 512;
    unsigned long long* bp = (unsigned long long*)(bits + row * 128) + w * 8;
#pragma unroll
    for (int k = 0; k < 8; ++k) {
      int v = ap[k * 64 + lane];
      unsigned long long mask = __ballot(v != 0);
      if (lane == 0) bp[k] = mask;
    }
    return;
  }

  // ---- h = x@W tile, s_dst, w = exp, write G^T (rows 0..519) ----
  const int tid = threadIdx.x;
  const int lane = tid & 63;
  const int h = tid >> 6;
  const int l15 = lane & 15, lg = lane >> 4;
  const int j0 = blockIdx.x * 16;

  {  // stage x tile once (16 rows x 512B), pre-permuted source
    int L = tid * 16;
    int row = L >> 9, b = L & 511;
    int sb = b ^ ((row & 7) << 4);
    gload_lds16((const char*)xb + (j0 + row) * 512 + sb, (char*)lx + L);
  }

  f32x4 acc[4] = {};
  for (int kc = 0; kc < 4; ++kc) {          // K chunks of 64
#pragma unroll
    for (int i = 0; i < 8; ++i) {           // stage W^T chunk [512 cols][128B]
      int L = (i * 512 + tid) * 16;
      int c = L >> 7, b = L & 127;
      int sb = b ^ ((c & 7) << 4);
      gload_lds16((const char*)wt + c * 512 + kc * 128 + sb, (char*)lw + L);
    }
    asm volatile("s_waitcnt vmcnt(0)");
    __syncthreads();
#pragma unroll
    for (int kk = 0; kk < 2; ++kk) {
      int kby = kk * 64 + lg * 16;
      s16x8 a = *(const s16x8*)((const char*)lx + l15 * 512 +
                                ((kc * 128 + kby) ^ ((l15 & 7) << 4)));
#pragma unroll
      for (int n = 0; n < 4; ++n) {
        int c = h * 64 + n * 16 + l15;
        s16x8 b = *(const s16x8*)((const char*)lw + c * 128 + (kby ^ ((c & 7) << 4)));
        acc[n] = __builtin_amdgcn_mfma_f32_16x16x32_bf16(a, b, acc[n], 0, 0, 0);
      }
    }
    __syncthreads();
  }

  float adv[4];
#pragma unroll
  for (int n = 0; n < 4; ++n) adv[n] = attn[h * 128 + 64 + n * 16 + l15];
#pragma unroll
  for (int r = 0; r < 4; ++r) {
    float p = acc[0][r] * adv[0] + acc[1][r] * adv[1] +
              acc[2][r] * adv[2] + acc[3][r] * adv[3];
#pragma unroll
    for (int m = 1; m < 16; m <<= 1) p += __shfl_xor(p, m);
    float w = expf(p);
    int node = j0 + lg * 4 + r;
#pragma unroll
    for (int n = 0; n < 4; ++n) {
      int c = h * 64 + n * 16 + l15;
      gt[c * GT_LD + node] = f2bf(acc[n][r] * w);
    }
    if (l15 == 0) gt[(512 + h) * GT_LD + node] = f2bf(w);
  }
}

// ---- kernel C: numer = adj(bits) @ G, split-K ---------------------------
// BM=128 BN=128 BK=64, 4 waves 2x2, single-buffer LDS 32KB, grid (160, S).
// A-tile: 1 u32 bit-load / thread (L2-resident 2MB) + in-register expand ->
// swizzled ds_write_b128. Next-tile bits prefetched during MFMA phase.
// GT rows 520..575 are stale; they only feed discarded output columns.
__global__ __launch_bounds__(256, 3) void k_gemm(const unsigned int* __restrict__ bits,
                                                 const unsigned short* __restrict__ GT,
                                                 float* __restrict__ out,
                                                 float* __restrict__ numx,
                                                 float* __restrict__ den,
                                                 int klen) {
  __shared__ unsigned short lA[128 * 64];   // 16KB
  __shared__ unsigned short lB[128 * 64];   // 16KB
  const int tid = threadIdx.x;
  const int lane = tid & 63, wid = tid >> 6;
  const int wr = wid >> 1, wc = wid & 1;
  const int l15 = lane & 15, lg = lane >> 4;

  int g = blockIdx.x;                       // 160 = 8*20 bijective XCD swizzle
  int swz = (g & 7) * 20 + (g >> 3);
  int bx = swz / 5, by = swz % 5;
  const int row0 = bx * 128, c0 = by * 128;

  const int s = blockIdx.y;
  float* num = (s == 0) ? out : (numx + (s - 1) * NUM_STRIDE);
  float* dens = den + s * (4096 * 8);

  // A-bits: thread covers row r, 32 K-cols starting at hf*32 of each tile
  const int r = tid >> 1, hf = tid & 1;
  const unsigned int* bitrow = bits + (row0 + r) * 128 + s * (klen >> 5) + hf;

  const char* Bbase = (const char*)GT + c0 * 8192 + (long)s * klen * 2;

  auto stageB = [&](int kt) {               // 4 gload_lds / thread
#pragma unroll
    for (int i = 0; i < 4; ++i) {
      int L = (i * 256 + tid) * 16;
      int rr = L >> 7, b = L & 127;
      int sb = b ^ ((rr & 7) << 4);
      gload_lds16(Bbase + rr * 8192 + kt * 128 + sb, (char*)lB + L);
    }
  };
  auto expandA = [&](uint32_t m) {          // 32 bits -> 32 bf16 in lA
#pragma unroll
    for (int q = 0; q < 4; ++q) {
      u32x4 w;
#pragma unroll
      for (int d = 0; d < 4; ++d) {
        int b = q * 8 + d * 2;
        w[d] = ((m >> b) & 1u) * 0x3F80u + ((m >> (b + 1)) & 1u) * 0x3F800000u;
      }
      int byte = (hf * 64 + q * 16) ^ ((r & 7) << 4);
      *(u32x4*)((char*)lA + r * 128 + byte) = w;
    }
  };

  f32x4 acc[4][4] = {};
  const int NKT = klen >> 6;

  uint32_t m = bitrow[0];
  for (int kt = 0; kt < NKT; ++kt) {
    uint32_t m2 = (kt < NKT - 1) ? bitrow[(kt + 1) * 2] : 0;  // prefetch
    stageB(kt);
    expandA(m);
    __syncthreads();                        // drains vmem + lds writes
#pragma unroll
    for (int kk = 0; kk < 2; ++kk) {
      int kby = kk * 64 + lg * 16;
      s16x8 a[4], b[4];
#pragma unroll
      for (int mm = 0; mm < 4; ++mm) {
        int rr = wr * 64 + mm * 16 + l15;
        a[mm] = *(const s16x8*)((const char*)lA + rr * 128 + (kby ^ ((rr & 7) << 4)));
      }
#pragma unroll
      for (int n = 0; n < 4; ++n) {
        int c = wc * 64 + n * 16 + l15;
        b[n] = *(const s16x8*)((const char*)lB + c * 128 + (kby ^ ((c & 7) << 4)));
      }
#pragma unroll
      for (int mm = 0; mm < 4; ++mm)
#pragma unroll
        for (int n = 0; n < 4; ++n)
          acc[mm][n] = __builtin_amdgcn_mfma_f32_16x16x32_bf16(a[mm], b[n], acc[mm][n], 0, 0, 0);
    }
    m = m2;
    __syncthreads();                        // reads done: safe to overwrite
  }

#pragma unroll
  for (int mm = 0; mm < 4; ++mm)
#pragma unroll
    for (int n = 0; n < 4; ++n) {
      int c = c0 + wc * 64 + n * 16 + l15;
#pragma unroll
      for (int rr = 0; rr < 4; ++rr) {
        int i = row0 + wr * 64 + mm * 16 + lg * 4 + rr;
        float v = acc[mm][n][rr];
        if (c < 512) num[i * 512 + c] = v;
        else if (c < 520) dens[i * 8 + (c - 512)] = v;
      }
    }
}

// ---- kernel D: out = (sum of split numerators) / (sum of split denoms) --
__global__ __launch_bounds__(256) void k_final(float* __restrict__ out,
                                               const float* __restrict__ numx,
                                               const float* __restrict__ den,
                                               int S) {
  int t = blockIdx.x * 256 + threadIdx.x;   // one float4 / thread
  int i = t >> 7, h = (t >> 4) & 7;
  f32x4 v = ((const f32x4*)out)[t];
  float d = den[i * 8 + h];
  for (int s = 1; s < S; ++s) {
    f32x4 u = ((const f32x4*)(numx + (s - 1) * NUM_STRIDE))[t];
    v.x += u.x; v.y += u.y; v.z += u.z; v.w += u.w;
    d += den[s * 4096 * 8 + i * 8 + h];
  }
  v.x /= d; v.y /= d; v.z /= d; v.w /= d;
  ((f32x4*)out)[t] = v;
}

extern "C" void kernel_launch(void* const* d_in, const int* in_sizes, int n_in,
                              void* d_out, int out_size, void* d_ws, size_t ws_size,
                              hipStream_t stream) {
  const float* x    = (const float*)d_in[0];
  const int*   adj  = (const int*)d_in[1];
  const float* W    = (const float*)d_in[2];
  const float* attn = (const float*)d_in[3];
  float* out = (float*)d_out;
  char* ws = (char*)d_ws;

  // ws layout
  unsigned int*   BITS = (unsigned int*)(ws);                  // 2 MB    adj bits
  unsigned short* GTp  = (unsigned short*)(ws + 2097152);      // 4.5 MB  G^T
  unsigned short* XB   = (unsigned short*)(ws + 6815744);      // 2 MB    x bf16
  unsigned short* WT   = (unsigned short*)(ws + 8912896);      // 256 KB  W^T bf16
  float*          DEN  = (float*)(ws + 9175040);               // 512 KB  denom (4 splits)
  float*          NUMX = (float*)(ws + 9699328);               // up to 24 MB partials

  int S = 1;
  if (ws_size >= 9699328ull + 3ull * NUM_STRIDE * 4 + 65536) S = 4;
  else if (ws_size >= 9699328ull + 1ull * NUM_STRIDE * 4 + 65536) S = 2;

  k_small<<<768, 512, 0, stream>>>(x, W, XB, WT);
  k_fat  <<<4352, 512, 0, stream>>>(adj, BITS, XB, WT, attn, GTp);
  dim3 ggrid(160, S);
  k_gemm <<<ggrid, 256, 0, stream>>>(BITS, GTp, out, NUMX, DEN, 4096 / S);
  k_final<<<2048, 256, 0, stream>>>(out, NUMX, DEN, S);
}

// Round 9
// 67.035 us; speedup vs baseline: 1.2297x; 1.2297x over previous
//
#include <hip/hip_runtime.h>
#include <hip/hip_bf16.h>
#include <stdint.h>

typedef __attribute__((ext_vector_type(4))) float  f32x4;
typedef __attribute__((ext_vector_type(8))) short  s16x8;
typedef __attribute__((ext_vector_type(4))) int    i32x4;
typedef __attribute__((ext_vector_type(4))) unsigned int u32x4;

#define NN 4096
#define GT_LD 4096
#define NUM_STRIDE (4096 * 512)

__device__ __forceinline__ unsigned short f2bf(float f) {
  uint32_t u = __builtin_bit_cast(uint32_t, f);
  u += 0x7FFF + ((u >> 16) & 1);           // RNE
  return (unsigned short)(u >> 16);
}

__device__ __forceinline__ void gload_lds16(const void* g, void* l) {
  __builtin_amdgcn_global_load_lds(
      (const __attribute__((address_space(1))) unsigned int*)g,
      (__attribute__((address_space(3))) unsigned int*)l, 16, 0, 0);
}

// ---- kernel A: conv_x + conv_wt fused (block ranges) --------------------
__global__ __launch_bounds__(512) void k_small(const float* __restrict__ x,
                                               const float* __restrict__ W,
                                               unsigned short* __restrict__ xb,
                                               unsigned short* __restrict__ wt) {
  int bid = blockIdx.x;
  if (bid < 512) {                          // x f32 -> bf16, 4/thread
    int t = bid * 512 + threadIdx.x;
    f32x4 v = ((const f32x4*)x)[t];
    uint64_t r = (uint64_t)f2bf(v.x) | ((uint64_t)f2bf(v.y) << 16) |
                 ((uint64_t)f2bf(v.z) << 32) | ((uint64_t)f2bf(v.w) << 48);
    ((uint64_t*)xb)[t] = r;
  } else {                                  // W (256x512) -> W^T (512x256) bf16
    int t = (bid - 512) * 512 + threadIdx.x;
    int c = t >> 8, k = t & 255;
    wt[t] = f2bf(W[k * 512 + c]);
  }
}

// ---- kernel B: fat kernel — h_gt blocks [0,256) + adj bit-pack blocks ---
__global__ __launch_bounds__(512) void k_fat(const int* __restrict__ adj,
                                             unsigned int* __restrict__ bits,
                                             const unsigned short* __restrict__ xb,
                                             const unsigned short* __restrict__ wt,
                                             const float* __restrict__ attn,
                                             unsigned short* __restrict__ gt) {
  __shared__ unsigned short lx[16 * 256];   // [16 rows][512B], XOR-swizzled
  __shared__ unsigned short lw[512 * 64];   // [512 cols][128B], XOR-swizzled

  if (blockIdx.x >= 256) {                  // ---- adj row -> 4096 bits ----
    int row = blockIdx.x - 256;             // one row per block
    int t = threadIdx.x;
    unsigned char* lbytes = (unsigned char*)lx;    // reuse h_gt's LDS
    const i32x4* ap = (const i32x4*)(adj + row * 4096) + 2 * t;
    i32x4 v0 = ap[0], v1 = ap[1];           // 8 adjacent ints, coalesced
    unsigned b = (v0.x ? 1u : 0u) | (v0.y ? 2u : 0u) |
                 (v0.z ? 4u : 0u) | (v0.w ? 8u : 0u) |
                 (v1.x ? 16u : 0u) | (v1.y ? 32u : 0u) |
                 (v1.z ? 64u : 0u) | (v1.w ? 128u : 0u);
    lbytes[t] = (unsigned char)b;           // byte t = cols [8t, 8t+8)
    __syncthreads();
    if (t < 128)                            // word t = cols [32t, 32t+32)
      bits[row * 128 + t] = ((const unsigned int*)lbytes)[t];
    return;
  }

  // ---- h = x@W tile, s_dst, w = exp, write G^T (rows 0..519) ----
  const int tid = threadIdx.x;
  const int lane = tid & 63;
  const int h = tid >> 6;
  const int l15 = lane & 15, lg = lane >> 4;
  const int j0 = blockIdx.x * 16;

  {  // stage x tile once (16 rows x 512B), pre-permuted source
    int L = tid * 16;
    int row = L >> 9, b = L & 511;
    int sb = b ^ ((row & 7) << 4);
    gload_lds16((const char*)xb + (j0 + row) * 512 + sb, (char*)lx + L);
  }

  f32x4 acc[4] = {};
  for (int kc = 0; kc < 4; ++kc) {          // K chunks of 64
#pragma unroll
    for (int i = 0; i < 8; ++i) {           // stage W^T chunk [512 cols][128B]
      int L = (i * 512 + tid) * 16;
      int c = L >> 7, b = L & 127;
      int sb = b ^ ((c & 7) << 4);
      gload_lds16((const char*)wt + c * 512 + kc * 128 + sb, (char*)lw + L);
    }
    asm volatile("s_waitcnt vmcnt(0)");
    __syncthreads();
#pragma unroll
    for (int kk = 0; kk < 2; ++kk) {
      int kby = kk * 64 + lg * 16;
      s16x8 a = *(const s16x8*)((const char*)lx + l15 * 512 +
                                ((kc * 128 + kby) ^ ((l15 & 7) << 4)));
#pragma unroll
      for (int n = 0; n < 4; ++n) {
        int c = h * 64 + n * 16 + l15;
        s16x8 b = *(const s16x8*)((const char*)lw + c * 128 + (kby ^ ((c & 7) << 4)));
        acc[n] = __builtin_amdgcn_mfma_f32_16x16x32_bf16(a, b, acc[n], 0, 0, 0);
      }
    }
    __syncthreads();
  }

  float adv[4];
#pragma unroll
  for (int n = 0; n < 4; ++n) adv[n] = attn[h * 128 + 64 + n * 16 + l15];
#pragma unroll
  for (int r = 0; r < 4; ++r) {
    float p = acc[0][r] * adv[0] + acc[1][r] * adv[1] +
              acc[2][r] * adv[2] + acc[3][r] * adv[3];
#pragma unroll
    for (int m = 1; m < 16; m <<= 1) p += __shfl_xor(p, m);
    float w = expf(p);
    int node = j0 + lg * 4 + r;
#pragma unroll
    for (int n = 0; n < 4; ++n) {
      int c = h * 64 + n * 16 + l15;
      gt[c * GT_LD + node] = f2bf(acc[n][r] * w);
    }
    if (l15 == 0) gt[(512 + h) * GT_LD + node] = f2bf(w);
  }
}

// ---- kernel C: numer = adj(bits) @ G, split-K ---------------------------
// BM=128 BN=128 BK=64, 4 waves 2x2, single-buffer LDS 32KB, grid (160, S).
// A-tile: 1 u32 bit-load / thread (L2-resident 2MB) + in-register expand ->
// swizzled ds_write_b128. Next-tile bits prefetched during MFMA phase.
// GT rows 520..575 are stale; they only feed discarded output columns.
__global__ __launch_bounds__(256, 3) void k_gemm(const unsigned int* __restrict__ bits,
                                                 const unsigned short* __restrict__ GT,
                                                 float* __restrict__ out,
                                                 float* __restrict__ numx,
                                                 float* __restrict__ den,
                                                 int klen) {
  __shared__ unsigned short lA[128 * 64];   // 16KB
  __shared__ unsigned short lB[128 * 64];   // 16KB
  const int tid = threadIdx.x;
  const int lane = tid & 63, wid = tid >> 6;
  const int wr = wid >> 1, wc = wid & 1;
  const int l15 = lane & 15, lg = lane >> 4;

  int g = blockIdx.x;                       // 160 = 8*20 bijective XCD swizzle
  int swz = (g & 7) * 20 + (g >> 3);
  int bx = swz / 5, by = swz % 5;
  const int row0 = bx * 128, c0 = by * 128;

  const int s = blockIdx.y;
  float* num = (s == 0) ? out : (numx + (s - 1) * NUM_STRIDE);
  float* dens = den + s * (4096 * 8);

  // A-bits: thread covers row r, 32 K-cols starting at hf*32 of each tile
  const int r = tid >> 1, hf = tid & 1;
  const unsigned int* bitrow = bits + (row0 + r) * 128 + s * (klen >> 5) + hf;

  const char* Bbase = (const char*)GT + c0 * 8192 + (long)s * klen * 2;

  auto stageB = [&](int kt) {               // 4 gload_lds / thread
#pragma unroll
    for (int i = 0; i < 4; ++i) {
      int L = (i * 256 + tid) * 16;
      int rr = L >> 7, b = L & 127;
      int sb = b ^ ((rr & 7) << 4);
      gload_lds16(Bbase + rr * 8192 + kt * 128 + sb, (char*)lB + L);
    }
  };
  auto expandA = [&](uint32_t m) {          // 32 bits -> 32 bf16 in lA
#pragma unroll
    for (int q = 0; q < 4; ++q) {
      u32x4 w;
#pragma unroll
      for (int d = 0; d < 4; ++d) {
        int b = q * 8 + d * 2;
        w[d] = ((m >> b) & 1u) * 0x3F80u + ((m >> (b + 1)) & 1u) * 0x3F800000u;
      }
      int byte = (hf * 64 + q * 16) ^ ((r & 7) << 4);
      *(u32x4*)((char*)lA + r * 128 + byte) = w;
    }
  };

  f32x4 acc[4][4] = {};
  const int NKT = klen >> 6;

  uint32_t m = bitrow[0];
  for (int kt = 0; kt < NKT; ++kt) {
    uint32_t m2 = (kt < NKT - 1) ? bitrow[(kt + 1) * 2] : 0;  // prefetch
    stageB(kt);
    expandA(m);
    __syncthreads();                        // drains vmem + lds writes
#pragma unroll
    for (int kk = 0; kk < 2; ++kk) {
      int kby = kk * 64 + lg * 16;
      s16x8 a[4], b[4];
#pragma unroll
      for (int mm = 0; mm < 4; ++mm) {
        int rr = wr * 64 + mm * 16 + l15;
        a[mm] = *(const s16x8*)((const char*)lA + rr * 128 + (kby ^ ((rr & 7) << 4)));
      }
#pragma unroll
      for (int n = 0; n < 4; ++n) {
        int c = wc * 64 + n * 16 + l15;
        b[n] = *(const s16x8*)((const char*)lB + c * 128 + (kby ^ ((c & 7) << 4)));
      }
#pragma unroll
      for (int mm = 0; mm < 4; ++mm)
#pragma unroll
        for (int n = 0; n < 4; ++n)
          acc[mm][n] = __builtin_amdgcn_mfma_f32_16x16x32_bf16(a[mm], b[n], acc[mm][n], 0, 0, 0);
    }
    m = m2;
    __syncthreads();                        // reads done: safe to overwrite
  }

#pragma unroll
  for (int mm = 0; mm < 4; ++mm)
#pragma unroll
    for (int n = 0; n < 4; ++n) {
      int c = c0 + wc * 64 + n * 16 + l15;
#pragma unroll
      for (int rr = 0; rr < 4; ++rr) {
        int i = row0 + wr * 64 + mm * 16 + lg * 4 + rr;
        float v = acc[mm][n][rr];
        if (c < 512) num[i * 512 + c] = v;
        else if (c < 520) dens[i * 8 + (c - 512)] = v;
      }
    }
}

// ---- kernel D: out = (sum of split numerators) / (sum of split denoms) --
__global__ __launch_bounds__(256) void k_final(float* __restrict__ out,
                                               const float* __restrict__ numx,
                                               const float* __restrict__ den,
                                               int S) {
  int t = blockIdx.x * 256 + threadIdx.x;   // one float4 / thread
  int i = t >> 7, h = (t >> 4) & 7;
  f32x4 v = ((const f32x4*)out)[t];
  float d = den[i * 8 + h];
  for (int s = 1; s < S; ++s) {
    f32x4 u = ((const f32x4*)(numx + (s - 1) * NUM_STRIDE))[t];
    v.x += u.x; v.y += u.y; v.z += u.z; v.w += u.w;
    d += den[s * 4096 * 8 + i * 8 + h];
  }
  v.x /= d; v.y /= d; v.z /= d; v.w /= d;
  ((f32x4*)out)[t] = v;
}

extern "C" void kernel_launch(void* const* d_in, const int* in_sizes, int n_in,
                              void* d_out, int out_size, void* d_ws, size_t ws_size,
                              hipStream_t stream) {
  const float* x    = (const float*)d_in[0];
  const int*   adj  = (const int*)d_in[1];
  const float* W    = (const float*)d_in[2];
  const float* attn = (const float*)d_in[3];
  float* out = (float*)d_out;
  char* ws = (char*)d_ws;

  // ws layout
  unsigned int*   BITS = (unsigned int*)(ws);                  // 2 MB    adj bits
  unsigned short* GTp  = (unsigned short*)(ws + 2097152);      // 4.5 MB  G^T
  unsigned short* XB   = (unsigned short*)(ws + 6815744);      // 2 MB    x bf16
  unsigned short* WT   = (unsigned short*)(ws + 8912896);      // 256 KB  W^T bf16
  float*          DEN  = (float*)(ws + 9175040);               // 512 KB  denom (4 splits)
  float*          NUMX = (float*)(ws + 9699328);               // up to 24 MB partials

  int S = 1;
  if (ws_size >= 9699328ull + 3ull * NUM_STRIDE * 4 + 65536) S = 4;
  else if (ws_size >= 9699328ull + 1ull * NUM_STRIDE * 4 + 65536) S = 2;

  k_small<<<768, 512, 0, stream>>>(x, W, XB, WT);
  k_fat  <<<4352, 512, 0, stream>>>(adj, BITS, XB, WT, attn, GTp);
  dim3 ggrid(160, S);
  k_gemm <<<ggrid, 256, 0, stream>>>(BITS, GTp, out, NUMX, DEN, 4096 / S);
  k_final<<<2048, 256, 0, stream>>>(out, NUMX, DEN, S);
}